// Round 8
// baseline (264.971 us; speedup 1.0000x reference)
//
#include <hip/hip_runtime.h>

#define Wd 640
#define Hd 512
#define NB 32
#define TW 64
#define TH2 32
#define RR 4
#define SW 72
#define ROWS (TH2 + RR)                    // 36 staged rows
constexpr int TILES_X = Wd / TW;           // 10
constexpr int TILES_Y = Hd / TH2;          // 16
constexpr int NBLK = TILES_X * TILES_Y * NB;   // 5120
constexpr int PLANE = ROWS * SW;           // 2592 dwords
constexpr float EPSC = 0.5f;

// ---------------- Kernel A: disparity warp (bilinear along x) ----------------
__global__ __launch_bounds__(256)
void warp_kernel(const float* __restrict__ disp, const float* __restrict__ pattern,
                 float* __restrict__ proj)
{
    int gid = blockIdx.x * 256 + threadIdx.x;   // one thread per 4 px
    int n = gid * 4;
    float4 d4 = *(const float4*)(disp + n);
    int u = n % Wd;
    int rowbase = ((n / Wd) % Hd) * Wd;
    float dv[4] = {d4.x, d4.y, d4.z, d4.w};
    #pragma unroll
    for (int j = 0; j < 4; ++j) {
        float x = (float)(u + j) - dv[j];
        x = fminf(fmaxf(x, 0.f), (float)(Wd - 1));
        float x0 = floorf(x);
        float w = x - x0;
        int i0 = (int)x0;
        int i1 = min(i0 + 1, Wd - 1);
        float g0 = pattern[rowbase + i0];
        float g1 = pattern[rowbase + i1];
        proj[n + j] = fmaf(w, g1 - g0, g0);
    }
}

// ---------------- census primitives ----------------
// c(x)=x/(eps+|x|);  ca-cb = (da*d2 - db*d1)/(d1*d2),  d1=eps+|da|, d2=eps+|db|
__device__ __forceinline__ void cne(float na, float nb, float ac, float bc,
                                    float& n, float& e)
{
    float da = na - ac;
    float db = nb - bc;
    float d1 = EPSC + fabsf(da);
    float d2 = EPSC + fabsf(db);
    n = fmaf(da, d2, -(db * d1));
    e = d1 * d2;                        // in [0.25, 2.25]
}

// Sum of 4 terms with ONE rcp
__device__ __forceinline__ float comb4(float n1, float e1, float n2, float e2,
                                       float n3, float e3, float n4, float e4)
{
    float e12 = e1 * e2, e34 = e3 * e4;
    float s12 = fmaf(fabsf(n2), e1, fabsf(n1) * e2);
    float s34 = fmaf(fabsf(n4), e3, fabsf(n3) * e4);
    float t   = fmaf(s34, e12, s12 * e34);
    return t * __builtin_amdgcn_rcpf(e12 * e34);
}

// load window row W (LDS rows base+W, cols lane..lane+8) into named regs
#define WLOAD(W) \
    wa0=p0[(W)*SW+0]; wa1=p0[(W)*SW+1]; wa2=p0[(W)*SW+2]; wa3=p0[(W)*SW+3]; \
    wa4=p0[(W)*SW+4]; wa5=p0[(W)*SW+5]; wa6=p0[(W)*SW+6]; wa7=p0[(W)*SW+7]; \
    wa8=p0[(W)*SW+8]; \
    wb0=p1[(W)*SW+0]; wb1=p1[(W)*SW+1]; wb2=p1[(W)*SW+2]; wb3=p1[(W)*SW+3]; \
    wb4=p1[(W)*SW+4]; wb5=p1[(W)*SW+5]; wb6=p1[(W)*SW+6]; wb7=p1[(W)*SW+7]; \
    wb8=p1[(W)*SW+8];

// capture center of pixel P (= this window's col 4) + its 4 right-half terms
#define CENTER(P, ACC) { \
    cA##P = wa4; cB##P = wb4; \
    float n0,e0,n1,e1,n2,e2,n3,e3; \
    cne(wa5,wb5,cA##P,cB##P,n0,e0); \
    cne(wa6,wb6,cA##P,cB##P,n1,e1); \
    cne(wa7,wb7,cA##P,cB##P,n2,e2); \
    cne(wa8,wb8,cA##P,cB##P,n3,e3); \
    if constexpr (EC) { n0*=m5; n1*=m6; n2*=m7; n3*=m8; } \
    ACC += comb4(n0,e0,n1,e1,n2,e2,n3,e3); }

// 9 terms of pixel P against current window row
#define ROWP(P, ACC) { \
    float n0,e0,n1,e1,n2,e2,n3,e3,n4,e4,n5,e5,n6,e6,n7,e7,n8,e8; \
    cne(wa0,wb0,cA##P,cB##P,n0,e0); \
    cne(wa1,wb1,cA##P,cB##P,n1,e1); \
    cne(wa2,wb2,cA##P,cB##P,n2,e2); \
    cne(wa3,wb3,cA##P,cB##P,n3,e3); \
    cne(wa4,wb4,cA##P,cB##P,n4,e4); \
    cne(wa5,wb5,cA##P,cB##P,n5,e5); \
    cne(wa6,wb6,cA##P,cB##P,n6,e6); \
    cne(wa7,wb7,cA##P,cB##P,n7,e7); \
    cne(wa8,wb8,cA##P,cB##P,n8,e8); \
    if constexpr (EC) { n0*=m0; n1*=m1; n2*=m2; n3*=m3; \
                        n5*=m5; n6*=m6; n7*=m7; n8*=m8; } \
    if constexpr (ER) { n0*=mv; n1*=mv; n2*=mv; n3*=mv; n4*=mv; \
                        n5*=mv; n6*=mv; n7*=mv; n8*=mv; } \
    ACC += comb4(n0,e0,n1,e1,n2,e2,n3,e3); \
    ACC += comb4(n5,e5,n6,e6,n7,e7,n8,e8); \
    ACC = fmaf(fabsf(n4), __builtin_amdgcn_rcpf(e4), ACC); }

template<bool EC, bool ER>
__device__ __forceinline__ float strip_sum(const float* __restrict__ p0,
                                           const float* __restrict__ p1,
                                           int x, int gr0)
{
    float m0,m1,m2,m3,m5,m6,m7,m8;
    if constexpr (EC) {
        m0 = ((unsigned)(x - 4) < (unsigned)Wd) ? 1.f : 0.f;
        m1 = ((unsigned)(x - 3) < (unsigned)Wd) ? 1.f : 0.f;
        m2 = ((unsigned)(x - 2) < (unsigned)Wd) ? 1.f : 0.f;
        m3 = ((unsigned)(x - 1) < (unsigned)Wd) ? 1.f : 0.f;
        m5 = ((unsigned)(x + 1) < (unsigned)Wd) ? 1.f : 0.f;
        m6 = ((unsigned)(x + 2) < (unsigned)Wd) ? 1.f : 0.f;
        m7 = ((unsigned)(x + 3) < (unsigned)Wd) ? 1.f : 0.f;
        m8 = ((unsigned)(x + 4) < (unsigned)Wd) ? 1.f : 0.f;
    }
    float wa0,wa1,wa2,wa3,wa4,wa5,wa6,wa7,wa8;
    float wb0,wb1,wb2,wb3,wb4,wb5,wb6,wb7,wb8;
    float cA0,cA1,cA2,cA3,cA4,cA5,cA6,cA7;
    float cB0,cB1,cB2,cB3,cB4,cB5,cB6,cB7;
    float acc0=0.f, acc1=0.f, acc2=0.f, acc3=0.f;

#define MVW(W) float mv = 1.f; if constexpr (ER) mv = (gr0 + (W) < Hd) ? 1.f : 0.f; (void)mv;

    { WLOAD(0)  CENTER(0,acc0) }
    { WLOAD(1)  MVW(1)  CENTER(1,acc1) ROWP(0,acc0) }
    { WLOAD(2)  MVW(2)  CENTER(2,acc2) ROWP(0,acc0) ROWP(1,acc1) }
    { WLOAD(3)  MVW(3)  CENTER(3,acc3) ROWP(0,acc0) ROWP(1,acc1) ROWP(2,acc2) }
    { WLOAD(4)  MVW(4)  CENTER(4,acc0) ROWP(0,acc0) ROWP(1,acc1) ROWP(2,acc2) ROWP(3,acc3) }
    { WLOAD(5)  MVW(5)  CENTER(5,acc1) ROWP(1,acc1) ROWP(2,acc2) ROWP(3,acc3) ROWP(4,acc0) }
    { WLOAD(6)  MVW(6)  CENTER(6,acc2) ROWP(2,acc2) ROWP(3,acc3) ROWP(4,acc0) ROWP(5,acc1) }
    { WLOAD(7)  MVW(7)  CENTER(7,acc3) ROWP(3,acc3) ROWP(4,acc0) ROWP(5,acc1) ROWP(6,acc2) }
    { WLOAD(8)  MVW(8)  ROWP(4,acc0) ROWP(5,acc1) ROWP(6,acc2) ROWP(7,acc3) }
    { WLOAD(9)  MVW(9)  ROWP(5,acc1) ROWP(6,acc2) ROWP(7,acc3) }
    { WLOAD(10) MVW(10) ROWP(6,acc2) ROWP(7,acc3) }
    { WLOAD(11) MVW(11) ROWP(7,acc3) }
#undef MVW
    return (acc0 + acc1) + (acc2 + acc3);
}

// ---------------- Kernel B: census over 64x32 tiles, 8-px column strips ----------------
// lane owns column x = tU*64 + (tid&63); warp w owns rows v0+8w .. v0+8w+7.
// All LDS reads stride-1 across lanes (conflict-free).
__global__ __launch_bounds__(256)
void census_kernel(const float* __restrict__ proj, const float* __restrict__ im,
                   float* __restrict__ partial)
{
    __shared__ float lds[2 * PLANE];            // [proj | im]

    const int tU = blockIdx.x, tV = blockIdx.y, b = blockIdx.z;
    const int tid = threadIdx.x;
    const float* pb = proj + (size_t)b * (Hd * Wd);
    const float* ib = im   + (size_t)b * (Hd * Wd);
    const int v0  = tV * TH2;
    const int u0g = tU * TW - RR;               // global col of LDS col 0

    const bool edgeC = (tU == 0) | (tU == TILES_X - 1);
    const bool edgeR = (tV == TILES_Y - 1);

    if (!edgeC && !edgeR) {
        // fast staging: all addresses in-bounds; float4 (u0g % 4 == 0)
        const float* pbase = pb + v0 * Wd + u0g;
        const float* ibase = ib + v0 * Wd + u0g;
        for (int f = tid; f < ROWS * 18; f += 256) {    // 648 float4 per plane
            int r = f / 18;
            int c = (f - 18 * r) * 4;
            *(float4*)&lds[r * SW + c]         = *(const float4*)(pbase + r * Wd + c);
            *(float4*)&lds[PLANE + r * SW + c] = *(const float4*)(ibase + r * Wd + c);
        }
    } else {
        for (int idx = tid; idx < PLANE; idx += 256) {
            int r = idx / SW;
            int c = idx - r * SW;
            int gv = min(v0 + r, Hd - 1);
            int gu = min(max(u0g + c, 0), Wd - 1);
            int off = gv * Wd + gu;
            lds[idx]         = pb[off];
            lds[PLANE + idx] = ib[off];
        }
    }
    __syncthreads();

    const int lane = tid & 63;                  // column within tile
    const int w    = tid >> 6;                  // strip index (8 rows each)
    const int x    = tU * TW + lane;            // global column
    const int gr0  = v0 + 8 * w;                // global row of strip pixel 0
    const float* p0 = lds + (8 * w) * SW + lane;
    const float* p1 = p0 + PLANE;

    float acc;
    if (!edgeC && !edgeR)      acc = strip_sum<false,false>(p0, p1, x, gr0);
    else if (edgeC && !edgeR)  acc = strip_sum<true, false>(p0, p1, x, gr0);
    else if (!edgeC)           acc = strip_sum<false,true >(p0, p1, x, gr0);
    else                       acc = strip_sum<true, true >(p0, p1, x, gr0);

    // block reduction -> one partial per block (deterministic)
    #pragma unroll
    for (int o = 32; o; o >>= 1) acc += __shfl_down(acc, o);
    __shared__ float wsum[4];
    if (lane == 0) wsum[w] = acc;
    __syncthreads();
    if (tid == 0) {
        float s = wsum[0] + wsum[1] + wsum[2] + wsum[3];
        partial[((int)blockIdx.z * gridDim.y + blockIdx.y) * gridDim.x + blockIdx.x] = s;
    }
}

// ---------------- Kernel C: final deterministic reduce ----------------
__global__ __launch_bounds__(1024)
void final_reduce(const float* __restrict__ partial, float* __restrict__ out)
{
    double s = 0.0;
    for (int i = threadIdx.x; i < NBLK; i += 1024) s += (double)partial[i];
    __shared__ double sm[1024];
    sm[threadIdx.x] = s;
    __syncthreads();
    for (int st = 512; st; st >>= 1) {
        if (threadIdx.x < st) sm[threadIdx.x] += sm[threadIdx.x + st];
        __syncthreads();
    }
    if (threadIdx.x == 0) {
        // val = 2 * S_half / (81 * B*H*W)   (half-space symmetry doubling)
        out[0] = (float)(sm[0] * (2.0 / (81.0 * (double)NB * Hd * Wd)));
    }
}

extern "C" void kernel_launch(void* const* d_in, const int* in_sizes, int n_in,
                              void* d_out, int out_size, void* d_ws, size_t ws_size,
                              hipStream_t stream)
{
    const float* disp    = (const float*)d_in[0];
    const float* im      = (const float*)d_in[1];
    const float* pattern = (const float*)d_in[2];
    float* out  = (float*)d_out;
    float* proj = out + 1;                      // output 1: pattern_proj
    float* partial = (float*)d_ws;              // 5120 floats scratch

    const int npx = NB * Hd * Wd;
    warp_kernel<<<npx / (256 * 4), 256, 0, stream>>>(disp, pattern, proj);

    dim3 grid(TILES_X, TILES_Y, NB);
    census_kernel<<<grid, 256, 0, stream>>>(proj, im, partial);

    final_reduce<<<1, 1024, 0, stream>>>(partial, out);
}

// Round 12
// 156.215 us; speedup vs baseline: 1.6962x; 1.6962x over previous
//
#include <hip/hip_runtime.h>

#define Wd 640
#define Hd 512
#define NB 32
#define TW 64
#define TH 16
#define RR 4
#define SW 72
constexpr int TILES_X = Wd / TW;   // 10
constexpr int TILES_Y = Hd / TH;   // 32
constexpr int NBLK = TILES_X * TILES_Y * NB;   // 10240
constexpr size_t HWsz = (size_t)Hd * Wd;
constexpr float EPSC = 0.5f;

typedef __fp16 h2_t __attribute__((ext_vector_type(2)));

__device__ __forceinline__ unsigned pack2(float a, float b)
{
    union { h2_t h; unsigned u; } c;
    c.h = __builtin_amdgcn_cvt_pkrtz(a, b);    // v_cvt_pkrtz_f16_f32
    return c.u;
}
__device__ __forceinline__ void unp2(unsigned u, float& a, float& b)
{
    union { unsigned u; h2_t h; } c; c.u = u;
    a = (float)c.h[0]; b = (float)c.h[1];
}

// ---------------- Kernel A: disparity warp + f16 pack of (proj, im) ----------------
__global__ __launch_bounds__(256)
void warp_pack(const float* __restrict__ disp, const float* __restrict__ pattern,
               const float* __restrict__ im, float* __restrict__ proj,
               unsigned* __restrict__ pk)
{
    int gid = blockIdx.x * 256 + threadIdx.x;   // one thread per 4 px
    int n = gid * 4;
    float4 d4 = *(const float4*)(disp + n);
    float4 i4 = *(const float4*)(im + n);
    int u = n % Wd;
    int rowbase = ((n / Wd) % Hd) * Wd;
    float dv[4] = {d4.x, d4.y, d4.z, d4.w};
    float iv[4] = {i4.x, i4.y, i4.z, i4.w};
    float pv[4];
    #pragma unroll
    for (int j = 0; j < 4; ++j) {
        float x = (float)(u + j) - dv[j];
        x = fminf(fmaxf(x, 0.f), (float)(Wd - 1));
        float x0 = floorf(x);
        float w = x - x0;
        int i0 = (int)x0;
        int i1 = min(i0 + 1, Wd - 1);
        float g0 = pattern[rowbase + i0];
        float g1 = pattern[rowbase + i1];
        pv[j] = fmaf(w, g1 - g0, g0);
    }
    *(float4*)(proj + n) = make_float4(pv[0], pv[1], pv[2], pv[3]);
    uint4 o = { pack2(pv[0], iv[0]), pack2(pv[1], iv[1]),
                pack2(pv[2], iv[2]), pack2(pv[3], iv[3]) };
    *(uint4*)(pk + n) = o;
}

// plain warp kernel (fallback path, ws too small)
__global__ __launch_bounds__(256)
void warp_kernel(const float* __restrict__ disp, const float* __restrict__ pattern,
                 float* __restrict__ proj)
{
    int gid = blockIdx.x * 256 + threadIdx.x;
    int n = gid * 4;
    float4 d4 = *(const float4*)(disp + n);
    int u = n % Wd;
    int rowbase = ((n / Wd) % Hd) * Wd;
    float dv[4] = {d4.x, d4.y, d4.z, d4.w};
    #pragma unroll
    for (int j = 0; j < 4; ++j) {
        float x = (float)(u + j) - dv[j];
        x = fminf(fmaxf(x, 0.f), (float)(Wd - 1));
        float x0 = floorf(x);
        float w = x - x0;
        int i0 = (int)x0;
        int i1 = min(i0 + 1, Wd - 1);
        float g0 = pattern[rowbase + i0];
        float g1 = pattern[rowbase + i1];
        proj[n + j] = fmaf(w, g1 - g0, g0);
    }
}

// ---------------- census math (r5-proven) ----------------
__device__ __forceinline__ void census_ne(float na, float nb, float ac, float bc,
                                          float& n, float& e)
{
    float da = na - ac;
    float db = nb - bc;
    float d1 = EPSC + fabsf(da);
    float d2 = EPSC + fabsf(db);
    n = fmaf(da, d2, -(db * d1));
    e = d1 * d2;                        // in [0.25, 2.25]
}

__device__ __forceinline__ float comb4(float n1, float e1, float n2, float e2,
                                       float n3, float e3, float n4, float e4)
{
    float e12 = e1 * e2, e34 = e3 * e4;
    float s12 = fmaf(fabsf(n2), e1, fabsf(n1) * e2);
    float s34 = fmaf(fabsf(n4), e3, fabsf(n3) * e4);
    float t   = fmaf(s34, e12, s12 * e34);
    return t * __builtin_amdgcn_rcpf(e12 * e34);
}

#define GRP4(ACC, xA0,xA1,xA2,xA3, xB0,xB1,xB2,xB3) { \
    float n0,e0,n1,e1,n2,e2,n3,e3;                    \
    census_ne(xA0,xB0,ca0,cb0,n0,e0);                 \
    census_ne(xA1,xB1,ca1,cb1,n1,e1);                 \
    census_ne(xA2,xB2,ca2,cb2,n2,e2);                 \
    census_ne(xA3,xB3,ca3,cb3,n3,e3);                 \
    ACC += comb4(n0,e0,n1,e1,n2,e2,n3,e3); }

#define GRPM(ACC, DW, xA0,xA1,xA2,xA3, xB0,xB1,xB2,xB3) { \
    float n0,e0,n1,e1,n2,e2,n3,e3;                    \
    census_ne(xA0,xB0,ca0,cb0,n0,e0);                 \
    census_ne(xA1,xB1,ca1,cb1,n1,e1);                 \
    census_ne(xA2,xB2,ca2,cb2,n2,e2);                 \
    census_ne(xA3,xB3,ca3,cb3,n3,e3);                 \
    n0 *= ((unsigned)(ub+0+(DW)) < (unsigned)Wd) ? mv : 0.f; \
    n1 *= ((unsigned)(ub+1+(DW)) < (unsigned)Wd) ? mv : 0.f; \
    n2 *= ((unsigned)(ub+2+(DW)) < (unsigned)Wd) ? mv : 0.f; \
    n3 *= ((unsigned)(ub+3+(DW)) < (unsigned)Wd) ? mv : 0.f; \
    ACC += comb4(n0,e0,n1,e1,n2,e2,n3,e3); }

#define NINE_GRPS(GM)                                             \
    GM(acc0, -4, ra0,ra1,ra2 ,ra3 , rb0,rb1,rb2 ,rb3 )            \
    GM(acc1, -3, ra1,ra2,ra3 ,ra4 , rb1,rb2,rb3 ,rb4 )            \
    GM(acc0, -2, ra2,ra3,ra4 ,ra5 , rb2,rb3,rb4 ,rb5 )            \
    GM(acc1, -1, ra3,ra4,ra5 ,ra6 , rb3,rb4,rb5 ,rb6 )            \
    GM(acc0,  0, ra4,ra5,ra6 ,ra7 , rb4,rb5,rb6 ,rb7 )            \
    GM(acc1,  1, ra5,ra6,ra7 ,ra8 , rb5,rb6,rb7 ,rb8 )            \
    GM(acc0,  2, ra6,ra7,ra8 ,ra9 , rb6,rb7,rb8 ,rb9 )            \
    GM(acc1,  3, ra7,ra8,ra9 ,ra10, rb7,rb8,rb9 ,rb10)            \
    GM(acc0,  4, ra8,ra9,ra10,ra11, rb8,rb9,rb10,rb11)

#define GRP4_NODW(ACC, DW, xA0,xA1,xA2,xA3, xB0,xB1,xB2,xB3) \
    GRP4(ACC, xA0,xA1,xA2,xA3, xB0,xB1,xB2,xB3)

// h2 window loads: 3 uint4 per row, unpack to named f32 scalars
#define LOADROW_H2(row)                                           \
    uint4 q0 = *(const uint4*)&sp[row][4 * tx];                   \
    uint4 q1 = *(const uint4*)&sp[row][4 * tx + 4];               \
    uint4 q2 = *(const uint4*)&sp[row][4 * tx + 8];               \
    float ra0,ra1,ra2,ra3,ra4,ra5,ra6,ra7,ra8,ra9,ra10,ra11;      \
    float rb0,rb1,rb2,rb3,rb4,rb5,rb6,rb7,rb8,rb9,rb10,rb11;      \
    unp2(q0.x, ra0, rb0); unp2(q0.y, ra1, rb1);                   \
    unp2(q0.z, ra2, rb2); unp2(q0.w, ra3, rb3);                   \
    unp2(q1.x, ra4, rb4); unp2(q1.y, ra5, rb5);                   \
    unp2(q1.z, ra6, rb6); unp2(q1.w, ra7, rb7);                   \
    unp2(q2.x, ra8, rb8); unp2(q2.y, ra9, rb9);                   \
    unp2(q2.z, ra10, rb10); unp2(q2.w, ra11, rb11);

#define LOADCTR_H2(row)                                           \
    uint4 q1 = *(const uint4*)&sp[row][4 * tx + 4];               \
    uint4 q2 = *(const uint4*)&sp[row][4 * tx + 8];               \
    float ra4,ra5,ra6,ra7,ra8,ra9,ra10,ra11;                      \
    float rb4,rb5,rb6,rb7,rb8,rb9,rb10,rb11;                      \
    unp2(q1.x, ra4, rb4); unp2(q1.y, ra5, rb5);                   \
    unp2(q1.z, ra6, rb6); unp2(q1.w, ra7, rb7);                   \
    unp2(q2.x, ra8, rb8); unp2(q2.y, ra9, rb9);                   \
    unp2(q2.z, ra10, rb10); unp2(q2.w, ra11, rb11);

// ---------------- Kernel B (h2): census over 64x16 tiles from packed buffer ----------------
__global__ __launch_bounds__(256)
void census_h2(const unsigned* __restrict__ pk, float* __restrict__ partial)
{
    __shared__ unsigned sp[TH + RR][SW];        // 20 x 72 u32 = 5.8 KB

    const int tU = blockIdx.x, tV = blockIdx.y, b = blockIdx.z;
    const int tid = threadIdx.x;
    const unsigned* pkb = pk + (size_t)b * HWsz;
    const int v0  = tV * TH;
    const int u0g = tU * TW - RR;

    const bool edge = (tU == 0) | (tU == TILES_X - 1) | (tV == TILES_Y - 1);

    if (!edge) {
        const unsigned* base = pkb + v0 * Wd + u0g;   // u0g % 4 == 0
        for (int f = tid; f < (TH + RR) * 18; f += 256) {
            int r = f / 18;
            int c = (f - 18 * r) * 4;
            *(uint4*)&sp[r][c] = *(const uint4*)(base + r * Wd + c);
        }
    } else {
        unsigned* spf = &sp[0][0];
        for (int idx = tid; idx < (TH + RR) * SW; idx += 256) {
            int r = idx / SW;
            int c = idx - r * SW;
            int gv = min(v0 + r, Hd - 1);
            int gu = min(max(u0g + c, 0), Wd - 1);
            spf[idx] = pkb[gv * Wd + gu];
        }
    }
    __syncthreads();

    const int ty = tid >> 4;                    // 0..15 (row in tile)
    const int tx = tid & 15;                    // 0..15 (group of 4 px)

    float acc0 = 0.f, acc1 = 0.f;
    const int ub = tU * TW + 4 * tx;
    const int v  = v0 + ty;
    float ca0, ca1, ca2, ca3, cb0, cb1, cb2, cb3;

    if (!edge) {
        {
            LOADCTR_H2(ty)
            ca0 = ra4; ca1 = ra5; ca2 = ra6; ca3 = ra7;
            cb0 = rb4; cb1 = rb5; cb2 = rb6; cb3 = rb7;
            GRP4(acc0, ra5,ra6,ra7,ra8 , rb5,rb6,rb7,rb8 )
            GRP4(acc1, ra6,ra7,ra8,ra9 , rb6,rb7,rb8,rb9 )
            GRP4(acc0, ra7,ra8,ra9,ra10, rb7,rb8,rb9,rb10)
            GRP4(acc1, ra8,ra9,ra10,ra11, rb8,rb9,rb10,rb11)
        }
        for (int dh = 1; dh <= RR; ++dh) {
            LOADROW_H2(ty + dh)
            NINE_GRPS(GRP4_NODW)
        }
    } else {
        {
            LOADCTR_H2(ty)
            ca0 = ra4; ca1 = ra5; ca2 = ra6; ca3 = ra7;
            cb0 = rb4; cb1 = rb5; cb2 = rb6; cb3 = rb7;
            float mv = 1.f;
            GRPM(acc0, 1, ra5,ra6,ra7,ra8 , rb5,rb6,rb7,rb8 )
            GRPM(acc1, 2, ra6,ra7,ra8,ra9 , rb6,rb7,rb8,rb9 )
            GRPM(acc0, 3, ra7,ra8,ra9,ra10, rb7,rb8,rb9,rb10)
            GRPM(acc1, 4, ra8,ra9,ra10,ra11, rb8,rb9,rb10,rb11)
        }
        for (int dh = 1; dh <= RR; ++dh) {
            LOADROW_H2(ty + dh)
            float mv = (v + dh < Hd) ? 1.f : 0.f;
            NINE_GRPS(GRPM)
        }
    }

    float acc = acc0 + acc1;
    #pragma unroll
    for (int o = 32; o; o >>= 1) acc += __shfl_down(acc, o);
    __shared__ float wsum[4];
    int wid = tid >> 6, lane = tid & 63;
    if (lane == 0) wsum[wid] = acc;
    __syncthreads();
    if (tid == 0) {
        float s = wsum[0] + wsum[1] + wsum[2] + wsum[3];
        partial[((int)blockIdx.z * gridDim.y + blockIdx.y) * gridDim.x + blockIdx.x] = s;
    }
}

// ---------------- Kernel B (f32 fallback, = round-5 kernel) ----------------
#define LOADROW_F(row)                                            \
    float4 tA0 = *(const float4*)&sa[row][4 * tx];                \
    float4 tA1 = *(const float4*)&sa[row][4 * tx + 4];            \
    float4 tA2 = *(const float4*)&sa[row][4 * tx + 8];            \
    float4 tB0 = *(const float4*)&sb[row][4 * tx];                \
    float4 tB1 = *(const float4*)&sb[row][4 * tx + 4];            \
    float4 tB2 = *(const float4*)&sb[row][4 * tx + 8];            \
    float ra0=tA0.x, ra1=tA0.y, ra2 =tA0.z, ra3 =tA0.w;           \
    float ra4=tA1.x, ra5=tA1.y, ra6 =tA1.z, ra7 =tA1.w;           \
    float ra8=tA2.x, ra9=tA2.y, ra10=tA2.z, ra11=tA2.w;           \
    float rb0=tB0.x, rb1=tB0.y, rb2 =tB0.z, rb3 =tB0.w;           \
    float rb4=tB1.x, rb5=tB1.y, rb6 =tB1.z, rb7 =tB1.w;           \
    float rb8=tB2.x, rb9=tB2.y, rb10=tB2.z, rb11=tB2.w;

__global__ __launch_bounds__(256)
void census_f32(const float* __restrict__ proj, const float* __restrict__ im,
                float* __restrict__ partial)
{
    __shared__ float sa[TH + RR][SW];
    __shared__ float sb[TH + RR][SW];

    const int tU = blockIdx.x, tV = blockIdx.y, b = blockIdx.z;
    const int tid = threadIdx.x;
    const float* pb = proj + (size_t)b * HWsz;
    const float* ib = im   + (size_t)b * HWsz;
    const int v0  = tV * TH;
    const int u0g = tU * TW - RR;

    const bool edge = (tU == 0) | (tU == TILES_X - 1) | (tV == TILES_Y - 1);

    if (!edge) {
        const float* pbase = pb + v0 * Wd + u0g;
        const float* ibase = ib + v0 * Wd + u0g;
        for (int f = tid; f < (TH + RR) * 18; f += 256) {
            int r = f / 18;
            int c = (f - 18 * r) * 4;
            *(float4*)&sa[r][c] = *(const float4*)(pbase + r * Wd + c);
            *(float4*)&sb[r][c] = *(const float4*)(ibase + r * Wd + c);
        }
    } else {
        for (int idx = tid; idx < (TH + RR) * SW; idx += 256) {
            int r = idx / SW;
            int c = idx - r * SW;
            int gv = min(v0 + r, Hd - 1);
            int gu = min(max(u0g + c, 0), Wd - 1);
            int off = gv * Wd + gu;
            sa[r][c] = pb[off];
            sb[r][c] = ib[off];
        }
    }
    __syncthreads();

    const int ty = tid >> 4;
    const int tx = tid & 15;

    float acc0 = 0.f, acc1 = 0.f;
    const int ub = tU * TW + 4 * tx;
    const int v  = v0 + ty;
    float ca0, ca1, ca2, ca3, cb0, cb1, cb2, cb3;

    if (!edge) {
        {
            LOADROW_F(ty)
            ca0 = ra4; ca1 = ra5; ca2 = ra6; ca3 = ra7;
            cb0 = rb4; cb1 = rb5; cb2 = rb6; cb3 = rb7;
            GRP4(acc0, ra5,ra6,ra7,ra8 , rb5,rb6,rb7,rb8 )
            GRP4(acc1, ra6,ra7,ra8,ra9 , rb6,rb7,rb8,rb9 )
            GRP4(acc0, ra7,ra8,ra9,ra10, rb7,rb8,rb9,rb10)
            GRP4(acc1, ra8,ra9,ra10,ra11, rb8,rb9,rb10,rb11)
        }
        for (int dh = 1; dh <= RR; ++dh) {
            LOADROW_F(ty + dh)
            NINE_GRPS(GRP4_NODW)
        }
    } else {
        {
            LOADROW_F(ty)
            ca0 = ra4; ca1 = ra5; ca2 = ra6; ca3 = ra7;
            cb0 = rb4; cb1 = rb5; cb2 = rb6; cb3 = rb7;
            float mv = 1.f;
            GRPM(acc0, 1, ra5,ra6,ra7,ra8 , rb5,rb6,rb7,rb8 )
            GRPM(acc1, 2, ra6,ra7,ra8,ra9 , rb6,rb7,rb8,rb9 )
            GRPM(acc0, 3, ra7,ra8,ra9,ra10, rb7,rb8,rb9,rb10)
            GRPM(acc1, 4, ra8,ra9,ra10,ra11, rb8,rb9,rb10,rb11)
        }
        for (int dh = 1; dh <= RR; ++dh) {
            LOADROW_F(ty + dh)
            float mv = (v + dh < Hd) ? 1.f : 0.f;
            NINE_GRPS(GRPM)
        }
    }

    float acc = acc0 + acc1;
    #pragma unroll
    for (int o = 32; o; o >>= 1) acc += __shfl_down(acc, o);
    __shared__ float wsum[4];
    int wid = tid >> 6, lane = tid & 63;
    if (lane == 0) wsum[wid] = acc;
    __syncthreads();
    if (tid == 0) {
        float s = wsum[0] + wsum[1] + wsum[2] + wsum[3];
        partial[((int)blockIdx.z * gridDim.y + blockIdx.y) * gridDim.x + blockIdx.x] = s;
    }
}

// ---------------- Kernel C: final deterministic reduce ----------------
__global__ __launch_bounds__(1024)
void final_reduce(const float* __restrict__ partial, float* __restrict__ out)
{
    double s = 0.0;
    for (int i = threadIdx.x; i < NBLK; i += 1024) s += (double)partial[i];
    __shared__ double sm[1024];
    sm[threadIdx.x] = s;
    __syncthreads();
    for (int st = 512; st; st >>= 1) {
        if (threadIdx.x < st) sm[threadIdx.x] += sm[threadIdx.x + st];
        __syncthreads();
    }
    if (threadIdx.x == 0) {
        // val = 2 * S_half / (81 * B*H*W)   (half-space symmetry doubling)
        out[0] = (float)(sm[0] * (2.0 / (81.0 * (double)NB * Hd * Wd)));
    }
}

extern "C" void kernel_launch(void* const* d_in, const int* in_sizes, int n_in,
                              void* d_out, int out_size, void* d_ws, size_t ws_size,
                              hipStream_t stream)
{
    const float* disp    = (const float*)d_in[0];
    const float* im      = (const float*)d_in[1];
    const float* pattern = (const float*)d_in[2];
    float* out  = (float*)d_out;
    float* proj = out + 1;                      // output 1: pattern_proj
    const int npx = NB * (int)HWsz;
    dim3 grid(TILES_X, TILES_Y, NB);

    const size_t need = HWsz * NB * sizeof(unsigned) + NBLK * sizeof(float);
    if (ws_size >= need) {
        unsigned* pk   = (unsigned*)d_ws;
        float* partial = (float*)(pk + HWsz * NB);
        warp_pack<<<npx / (256 * 4), 256, 0, stream>>>(disp, pattern, im, proj, pk);
        census_h2<<<grid, 256, 0, stream>>>(pk, partial);
        final_reduce<<<1, 1024, 0, stream>>>(partial, out);
    } else {
        float* partial = (float*)d_ws;
        warp_kernel<<<npx / (256 * 4), 256, 0, stream>>>(disp, pattern, proj);
        census_f32<<<grid, 256, 0, stream>>>(proj, im, partial);
        final_reduce<<<1, 1024, 0, stream>>>(partial, out);
    }
}

// Round 13
// 120.807 us; speedup vs baseline: 2.1934x; 1.2931x over previous
//
#include <hip/hip_runtime.h>

#define Wd 640
#define Hd 512
#define NB 32
#define TW 64
#define TH 16
#define RR 4
#define SWP 38                      // LDS row stride in u32 pairs (36 used + 2 pad)
constexpr int TILES_X = Wd / TW;   // 10
constexpr int TILES_Y = Hd / TH;   // 32
constexpr int NBLK = TILES_X * TILES_Y * NB;   // 10240
constexpr size_t HWsz = (size_t)Hd * Wd;

typedef __fp16 h2 __attribute__((ext_vector_type(2)));
union HU { unsigned u; h2 h; };
__device__ __forceinline__ h2 u2h(unsigned u){ HU c; c.u = u; return c.h; }
__device__ __forceinline__ h2 habs2(h2 x){ HU c; c.h = x; c.u &= 0x7fff7fffu; return c.h; }
__device__ __forceinline__ unsigned pack2(float a, float b)
{
    HU c; c.h = __builtin_amdgcn_cvt_pkrtz(a, b); return c.u;
}

// ---------------- Kernel A: disparity warp (r5 version) ----------------
__global__ __launch_bounds__(256)
void warp_kernel(const float* __restrict__ disp, const float* __restrict__ pattern,
                 float* __restrict__ proj)
{
    int gid = blockIdx.x * 256 + threadIdx.x;
    int n = gid * 4;
    float4 d4 = *(const float4*)(disp + n);
    int u = n % Wd;
    int rowbase = ((n / Wd) % Hd) * Wd;
    float dv[4] = {d4.x, d4.y, d4.z, d4.w};
    #pragma unroll
    for (int j = 0; j < 4; ++j) {
        float x = (float)(u + j) - dv[j];
        x = fminf(fmaxf(x, 0.f), (float)(Wd - 1));
        float x0 = floorf(x);
        float w = x - x0;
        int i0 = (int)x0;
        int i1 = min(i0 + 1, Wd - 1);
        float g0 = pattern[rowbase + i0];
        float g1 = pattern[rowbase + i1];
        proj[n + j] = fmaf(w, g1 - g0, g0);
    }
}

// ---------------- packed census primitives ----------------
// packet: 2 terms (pixel pair) for one offset. n = da*d2 - db*d1, e = d1*d2
#define PKTM(CA,CB, NAu,NBu, MM, N,E) {            \
    h2 _da = u2h(NAu) - CA;                        \
    h2 _db = u2h(NBu) - CB;                        \
    h2 _d1 = h05 + habs2(_da);                     \
    h2 _d2 = h05 + habs2(_db);                     \
    N = _da * _d2 - _db * _d1;                     \
    if constexpr (EC) N = N * u2h(MM);             \
    E = _d1 * _d2; }

// L1 combine of 2 packets: sp = |n1|e2 + |n2|e1, ep = e1*e2
#define L1C(N1,E1,N2,E2, SP,EP) {                  \
    SP = habs2(N1) * E2 + habs2(N2) * E1;          \
    EP = E1 * E2; }

// unpack packed (s,e) -> two f32 acc contributions
#define UNP(S,E, MV, P0,P1) {                      \
    float _sl = (float)S[0], _sh = (float)S[1];    \
    float _el = (float)E[0], _eh = (float)E[1];    \
    if constexpr (ER) { _sl *= MV; _sh *= MV; }    \
    P0 = fmaf(_sl, __builtin_amdgcn_rcpf(_el), P0);\
    P1 = fmaf(_sh, __builtin_amdgcn_rcpf(_eh), P1); }

// full 9-offset row for one pixel-pair job
#define ROWJOB(CA,CB, A0,A1,A2,A3,A4,A5,A6,A7,A8,  \
                      B0,B1,B2,B3,B4,B5,B6,B7,B8,  \
                      M0,M1,M2,M3,M4,M5,M6,M7,M8, MV, P0,P1) { \
    h2 n0,e0,n1,e1,n2,e2,n3,e3,n4,e4,n5,e5,n6,e6,n7,e7,n8,e8; \
    PKTM(CA,CB, A0,B0, M0, n0,e0)                  \
    PKTM(CA,CB, A1,B1, M1, n1,e1)                  \
    PKTM(CA,CB, A2,B2, M2, n2,e2)                  \
    PKTM(CA,CB, A3,B3, M3, n3,e3)                  \
    PKTM(CA,CB, A4,B4, M4, n4,e4)                  \
    PKTM(CA,CB, A5,B5, M5, n5,e5)                  \
    PKTM(CA,CB, A6,B6, M6, n6,e6)                  \
    PKTM(CA,CB, A7,B7, M7, n7,e7)                  \
    PKTM(CA,CB, A8,B8, M8, n8,e8)                  \
    h2 sA,eA,sB,eB,s4,e4t;                         \
    L1C(n0,e0,n1,e1, sA,eA)                        \
    L1C(n2,e2,n3,e3, sB,eB)                        \
    s4 = sA*eB + sB*eA; e4t = eA*eB;               \
    UNP(s4,e4t, MV, P0,P1)                         \
    L1C(n4,e4,n5,e5, sA,eA)                        \
    L1C(n6,e6,n7,e7, sB,eB)                        \
    s4 = sA*eB + sB*eA; e4t = eA*eB;               \
    { h2 na8 = habs2(n8);                          \
      s4 = s4*e8 + na8*e4t; e4t = e4t*e8; }        \
    UNP(s4,e4t, MV, P0,P1) }

// center row: right-half offsets +1..+4 only (no ER: center rows always valid)
#define CTR4(CA,CB, A1,A2,A3,A4, B1,B2,B3,B4, M1,M2,M3,M4, P0,P1) { \
    h2 n1,e1,n2,e2,n3,e3,n4,e4;                    \
    PKTM(CA,CB, A1,B1, M1, n1,e1)                  \
    PKTM(CA,CB, A2,B2, M2, n2,e2)                  \
    PKTM(CA,CB, A3,B3, M3, n3,e3)                  \
    PKTM(CA,CB, A4,B4, M4, n4,e4)                  \
    h2 sA,eA,sB,eB,s4,e4t;                         \
    L1C(n1,e1,n2,e2, sA,eA)                        \
    L1C(n3,e3,n4,e4, sB,eB)                        \
    s4 = sA*eB + sB*eA; e4t = eA*eB;               \
    { float _sl = (float)s4[0], _sh = (float)s4[1];            \
      float _el = (float)e4t[0], _eh = (float)e4t[1];          \
      P0 = fmaf(_sl, __builtin_amdgcn_rcpf(_el), P0);          \
      P1 = fmaf(_sh, __builtin_amdgcn_rcpf(_eh), P1); } }

#define LOADW(ROW)                                              \
    { const uint2* _pa = (const uint2*)&sA[(ROW)*SWP + 2*tx];   \
      const uint2* _pb = (const uint2*)&sB[(ROW)*SWP + 2*tx];   \
      uint2 _a0 = _pa[0], _a1 = _pa[1], _a2 = _pa[2];           \
      uint2 _b0 = _pb[0], _b1 = _pb[1], _b2 = _pb[2];           \
      wa0=_a0.x; wa1=_a0.y; wa2=_a1.x; wa3=_a1.y; wa4=_a2.x; wa5=_a2.y; \
      wb0=_b0.x; wb1=_b0.y; wb2=_b1.x; wb3=_b1.y; wb4=_b2.x; wb5=_b2.y; }

#define ALIGNS5                                                 \
    xa0 = __builtin_amdgcn_alignbit(wa1, wa0, 16);              \
    xa1 = __builtin_amdgcn_alignbit(wa2, wa1, 16);              \
    xa2 = __builtin_amdgcn_alignbit(wa3, wa2, 16);              \
    xa3 = __builtin_amdgcn_alignbit(wa4, wa3, 16);              \
    xa4 = __builtin_amdgcn_alignbit(wa5, wa4, 16);              \
    xb0 = __builtin_amdgcn_alignbit(wb1, wb0, 16);              \
    xb1 = __builtin_amdgcn_alignbit(wb2, wb1, 16);              \
    xb2 = __builtin_amdgcn_alignbit(wb3, wb2, 16);              \
    xb3 = __builtin_amdgcn_alignbit(wb4, wb3, 16);              \
    xb4 = __builtin_amdgcn_alignbit(wb5, wb4, 16);

template<bool EC, bool ER>
__device__ __forceinline__ float strip_sum(const unsigned* __restrict__ sA,
                                           const unsigned* __restrict__ sB,
                                           int ty, int tx, int ub, int v0)
{
    const h2 h05 = { (__fp16)0.5f, (__fp16)0.5f };
    // masks m[k], k = column offset from ub, k in [-4, 6]
    unsigned m_m4=0,m_m3=0,m_m2=0,m_m1=0,m_0=0,m_p1=0,m_p2=0,m_p3=0,m_p4=0,m_p5=0,m_p6=0;
    if constexpr (EC) {
        auto mk = [&](int k)->unsigned {
            unsigned lo = ((unsigned)(ub + k)     < (unsigned)Wd) ? 0x3C00u : 0u;
            unsigned hi = ((unsigned)(ub + k + 1) < (unsigned)Wd) ? 0x3C00u : 0u;
            return lo | (hi << 16);
        };
        m_m4=mk(-4); m_m3=mk(-3); m_m2=mk(-2); m_m1=mk(-1); m_0=mk(0);
        m_p1=mk(1);  m_p2=mk(2);  m_p3=mk(3);  m_p4=mk(4);  m_p5=mk(5); m_p6=mk(6);
    }

    unsigned wa0,wa1,wa2,wa3,wa4,wa5, wb0,wb1,wb2,wb3,wb4,wb5;
    unsigned xa0,xa1,xa2,xa3,xa4, xb0,xb1,xb2,xb3,xb4;
    float p00=0.f, p01=0.f, p10=0.f, p11=0.f;

    // ---- center row ----
    LOADW(ty)
    ALIGNS5
    h2 CA0 = u2h(wa2), CB0 = u2h(wb2);   // job 0 centers (px ub, ub+1)
    h2 CA1 = u2h(wa3), CB1 = u2h(wb3);   // job 1 centers (px ub+2, ub+3)
    CTR4(CA0,CB0, xa2,wa3,xa3,wa4, xb2,wb3,xb3,wb4, m_p1,m_p2,m_p3,m_p4, p00,p01)
    CTR4(CA1,CB1, xa3,wa4,xa4,wa5, xb3,wb4,xb4,wb5, m_p3,m_p4,m_p5,m_p6, p10,p11)

    // ---- 4 lower rows ----
    for (int dh = 1; dh <= RR; ++dh) {
        LOADW(ty + dh)
        ALIGNS5
        float mv = 1.f;
        if constexpr (ER) mv = (v0 + ty + dh < Hd) ? 1.f : 0.f;
        (void)mv;
        ROWJOB(CA0,CB0, wa0,xa0,wa1,xa1,wa2,xa2,wa3,xa3,wa4,
                        wb0,xb0,wb1,xb1,wb2,xb2,wb3,xb3,wb4,
                        m_m4,m_m3,m_m2,m_m1,m_0,m_p1,m_p2,m_p3,m_p4, mv, p00,p01)
        ROWJOB(CA1,CB1, wa1,xa1,wa2,xa2,wa3,xa3,wa4,xa4,wa5,
                        wb1,xb1,wb2,xb2,wb3,xb3,wb4,xb4,wb5,
                        m_m2,m_m1,m_0,m_p1,m_p2,m_p3,m_p4,m_p5,m_p6, mv, p10,p11)
    }
    return (p00 + p01) + (p10 + p11);
}

// ---------------- Kernel B: packed-pair census over 64x16 tiles ----------------
__global__ __launch_bounds__(256)
void census_pk(const float* __restrict__ proj, const float* __restrict__ im,
               float* __restrict__ partial)
{
    __shared__ unsigned sA[(TH + RR) * SWP];   // proj pairs, 20 x 38 u32 = 3040 B
    __shared__ unsigned sB[(TH + RR) * SWP];   // im pairs

    const int tU = blockIdx.x, tV = blockIdx.y, b = blockIdx.z;
    const int tid = threadIdx.x;
    const float* pb = proj + (size_t)b * HWsz;
    const float* ib = im   + (size_t)b * HWsz;
    const int v0  = tV * TH;
    const int u0g = tU * TW - 2 * RR / 2 * 2;   // = tU*TW - 4 (LDS col0 global col, even)

    const bool edgeC = (tU == 0) | (tU == TILES_X - 1);
    const bool edgeR = (tV == TILES_Y - 1);

    if (!edgeC && !edgeR) {
        // fast staging: float4 loads (2 pairs), pack, uint2 LDS store
        const float* pbase = pb + v0 * Wd + u0g;
        const float* ibase = ib + v0 * Wd + u0g;
        for (int f = tid; f < (TH + RR) * 18; f += 256) {
            int r = f / 18;
            int c4 = (f - 18 * r) * 4;            // px col in LDS window
            float4 va = *(const float4*)(pbase + r * Wd + c4);
            float4 vb = *(const float4*)(ibase + r * Wd + c4);
            uint2 qa = { pack2(va.x, va.y), pack2(va.z, va.w) };
            uint2 qb = { pack2(vb.x, vb.y), pack2(vb.z, vb.w) };
            *(uint2*)&sA[r * SWP + c4 / 2] = qa;
            *(uint2*)&sB[r * SWP + c4 / 2] = qb;
        }
    } else {
        for (int p = tid; p < (TH + RR) * 36; p += 256) {
            int r = p / 36;
            int q = p - 36 * r;
            int gv = min(v0 + r, Hd - 1);
            int g0 = min(max(u0g + 2 * q,     0), Wd - 1);
            int g1 = min(max(u0g + 2 * q + 1, 0), Wd - 1);
            const float* pr = pb + (size_t)gv * Wd;
            const float* irow = ib + (size_t)gv * Wd;
            sA[r * SWP + q] = pack2(pr[g0],   pr[g1]);
            sB[r * SWP + q] = pack2(irow[g0], irow[g1]);
        }
    }
    __syncthreads();

    const int ty = tid >> 4;                    // 0..15 (row in tile)
    const int tx = tid & 15;                    // 0..15 (group of 4 px = 2 pairs)
    const int ub = tU * TW + 4 * tx;            // global col of px 0

    float acc;
    if (!edgeC && !edgeR)      acc = strip_sum<false,false>(sA, sB, ty, tx, ub, v0);
    else if (edgeC && !edgeR)  acc = strip_sum<true, false>(sA, sB, ty, tx, ub, v0);
    else if (!edgeC)           acc = strip_sum<false,true >(sA, sB, ty, tx, ub, v0);
    else                       acc = strip_sum<true, true >(sA, sB, ty, tx, ub, v0);

    // block reduction -> one partial per block (deterministic)
    #pragma unroll
    for (int o = 32; o; o >>= 1) acc += __shfl_down(acc, o);
    __shared__ float wsum[4];
    int wid = tid >> 6, lane = tid & 63;
    if (lane == 0) wsum[wid] = acc;
    __syncthreads();
    if (tid == 0) {
        float s = wsum[0] + wsum[1] + wsum[2] + wsum[3];
        partial[((int)blockIdx.z * gridDim.y + blockIdx.y) * gridDim.x + blockIdx.x] = s;
    }
}

// ---------------- Kernel C: final deterministic reduce ----------------
__global__ __launch_bounds__(1024)
void final_reduce(const float* __restrict__ partial, float* __restrict__ out)
{
    double s = 0.0;
    for (int i = threadIdx.x; i < NBLK; i += 1024) s += (double)partial[i];
    __shared__ double sm[1024];
    sm[threadIdx.x] = s;
    __syncthreads();
    for (int st = 512; st; st >>= 1) {
        if (threadIdx.x < st) sm[threadIdx.x] += sm[threadIdx.x + st];
        __syncthreads();
    }
    if (threadIdx.x == 0) {
        // val = 2 * S_half / (81 * B*H*W)   (half-space symmetry doubling)
        out[0] = (float)(sm[0] * (2.0 / (81.0 * (double)NB * Hd * Wd)));
    }
}

extern "C" void kernel_launch(void* const* d_in, const int* in_sizes, int n_in,
                              void* d_out, int out_size, void* d_ws, size_t ws_size,
                              hipStream_t stream)
{
    const float* disp    = (const float*)d_in[0];
    const float* im      = (const float*)d_in[1];
    const float* pattern = (const float*)d_in[2];
    float* out  = (float*)d_out;
    float* proj = out + 1;                      // output 1: pattern_proj
    float* partial = (float*)d_ws;              // 10240 floats scratch

    const int npx = NB * (int)HWsz;
    warp_kernel<<<npx / (256 * 4), 256, 0, stream>>>(disp, pattern, proj);

    dim3 grid(TILES_X, TILES_Y, NB);
    census_pk<<<grid, 256, 0, stream>>>(proj, im, partial);

    final_reduce<<<1, 1024, 0, stream>>>(partial, out);
}

// Round 14
// 117.800 us; speedup vs baseline: 2.2493x; 1.0255x over previous
//
#include <hip/hip_runtime.h>

#define Wd 640
#define Hd 512
#define NB 32
#define TW 64
#define TH 16
#define RR 4
#define SWP 38                      // LDS row stride in u32 pairs (36 used + 2 pad)
constexpr int TILES_X = Wd / TW;   // 10
constexpr int TILES_Y = Hd / TH;   // 32
constexpr int NBLK = TILES_X * TILES_Y * NB;   // 10240
constexpr size_t HWsz = (size_t)Hd * Wd;

typedef __fp16 h2 __attribute__((ext_vector_type(2)));
union HU { unsigned u; h2 h; };
__device__ __forceinline__ h2 u2h(unsigned u){ HU c; c.u = u; return c.h; }
__device__ __forceinline__ h2 habs2(h2 x){ HU c; c.h = x; c.u &= 0x7fff7fffu; return c.h; }
__device__ __forceinline__ unsigned pack2(float a, float b)
{
    HU c; c.h = __builtin_amdgcn_cvt_pkrtz(a, b); return c.u;
}

// ---------------- Kernel A: disparity warp ----------------
__global__ __launch_bounds__(256)
void warp_kernel(const float* __restrict__ disp, const float* __restrict__ pattern,
                 float* __restrict__ proj)
{
    int gid = blockIdx.x * 256 + threadIdx.x;
    int n = gid * 4;
    float4 d4 = *(const float4*)(disp + n);
    int u = n % Wd;
    int rowbase = ((n / Wd) % Hd) * Wd;
    float dv[4] = {d4.x, d4.y, d4.z, d4.w};
    #pragma unroll
    for (int j = 0; j < 4; ++j) {
        float x = (float)(u + j) - dv[j];
        x = fminf(fmaxf(x, 0.f), (float)(Wd - 1));
        float x0 = floorf(x);
        float w = x - x0;
        int i0 = (int)x0;
        int i1 = min(i0 + 1, Wd - 1);
        float g0 = pattern[rowbase + i0];
        float g1 = pattern[rowbase + i1];
        proj[n + j] = fmaf(w, g1 - g0, g0);
    }
}

// ---------------- packed census primitives ----------------
// packet: 2 terms (pixel pair) for one offset. n = da*d2 - db*d1, e = d1*d2
#define PKTM(CA,CB, NAu,NBu, MM, N,E) {            \
    h2 _da = u2h(NAu) - CA;                        \
    h2 _db = u2h(NBu) - CB;                        \
    h2 _d1 = h05 + habs2(_da);                     \
    h2 _d2 = h05 + habs2(_db);                     \
    N = _da * _d2 - _db * _d1;                     \
    if constexpr (EC) N = N * u2h(MM);             \
    E = _d1 * _d2; }

// L1 combine of 2 packets: sp = |n1|e2 + |n2|e1, ep = e1*e2
#define L1C(N1,E1,N2,E2, SP,EP) {                  \
    SP = habs2(N1) * E2 + habs2(N2) * E1;          \
    EP = E1 * E2; }

// unpack packed (s,e) -> two f32 acc contributions
#define UNP(S,E, MV, P0,P1) {                      \
    float _sl = (float)S[0], _sh = (float)S[1];    \
    float _el = (float)E[0], _eh = (float)E[1];    \
    if constexpr (ER) { _sl *= MV; _sh *= MV; }    \
    P0 = fmaf(_sl, __builtin_amdgcn_rcpf(_el), P0);\
    P1 = fmaf(_sh, __builtin_amdgcn_rcpf(_eh), P1); }

// full 9-offset row for one pixel-pair job -> ONE merged rational + ONE unpack
#define ROWJOB(CA,CB, A0,A1,A2,A3,A4,A5,A6,A7,A8,  \
                      B0,B1,B2,B3,B4,B5,B6,B7,B8,  \
                      M0,M1,M2,M3,M4,M5,M6,M7,M8, MV, P0,P1) { \
    h2 n0,e0,n1,e1,n2,e2,n3,e3,n4,e4,n5,e5,n6,e6,n7,e7,n8,e8; \
    PKTM(CA,CB, A0,B0, M0, n0,e0)                  \
    PKTM(CA,CB, A1,B1, M1, n1,e1)                  \
    PKTM(CA,CB, A2,B2, M2, n2,e2)                  \
    PKTM(CA,CB, A3,B3, M3, n3,e3)                  \
    PKTM(CA,CB, A4,B4, M4, n4,e4)                  \
    PKTM(CA,CB, A5,B5, M5, n5,e5)                  \
    PKTM(CA,CB, A6,B6, M6, n6,e6)                  \
    PKTM(CA,CB, A7,B7, M7, n7,e7)                  \
    PKTM(CA,CB, A8,B8, M8, n8,e8)                  \
    h2 s01,e01,s23,e23,s45,e45,s67,e67;            \
    L1C(n0,e0,n1,e1, s01,e01)                      \
    L1C(n2,e2,n3,e3, s23,e23)                      \
    L1C(n4,e4,n5,e5, s45,e45)                      \
    L1C(n6,e6,n7,e7, s67,e67)                      \
    h2 sL = s01*e23 + s23*e01;  h2 eL = e01*e23;   \
    h2 sR = s45*e67 + s67*e45;  h2 eR = e45*e67;   \
    sR = sR*e8 + habs2(n8)*eR;  eR = eR*e8;        \
    h2 S = sL*eR + sR*eL;       h2 E = eL*eR;      \
    UNP(S,E, MV, P0,P1) }

// center row: right-half offsets +1..+4 only (center rows always row-valid)
#define CTR4(CA,CB, A1,A2,A3,A4, B1,B2,B3,B4, M1,M2,M3,M4, P0,P1) { \
    h2 n1,e1,n2,e2,n3,e3,n4,e4;                    \
    PKTM(CA,CB, A1,B1, M1, n1,e1)                  \
    PKTM(CA,CB, A2,B2, M2, n2,e2)                  \
    PKTM(CA,CB, A3,B3, M3, n3,e3)                  \
    PKTM(CA,CB, A4,B4, M4, n4,e4)                  \
    h2 sA,eA,sB,eB,s4,e4t;                         \
    L1C(n1,e1,n2,e2, sA,eA)                        \
    L1C(n3,e3,n4,e4, sB,eB)                        \
    s4 = sA*eB + sB*eA; e4t = eA*eB;               \
    { float _sl = (float)s4[0], _sh = (float)s4[1];            \
      float _el = (float)e4t[0], _eh = (float)e4t[1];          \
      P0 = fmaf(_sl, __builtin_amdgcn_rcpf(_el), P0);          \
      P1 = fmaf(_sh, __builtin_amdgcn_rcpf(_eh), P1); } }

// window row D (literal): 3 uint2 per plane at byte-immediate offsets off base ptrs
#define LOADW(D)                                                \
    { const uint2* _pa = (const uint2*)(pa + (D) * SWP);        \
      const uint2* _pb = (const uint2*)(pb + (D) * SWP);        \
      uint2 _a0 = _pa[0], _a1 = _pa[1], _a2 = _pa[2];           \
      uint2 _b0 = _pb[0], _b1 = _pb[1], _b2 = _pb[2];           \
      wa0=_a0.x; wa1=_a0.y; wa2=_a1.x; wa3=_a1.y; wa4=_a2.x; wa5=_a2.y; \
      wb0=_b0.x; wb1=_b0.y; wb2=_b1.x; wb3=_b1.y; wb4=_b2.x; wb5=_b2.y; }

#define ALIGNS5                                                 \
    xa0 = __builtin_amdgcn_alignbit(wa1, wa0, 16);              \
    xa1 = __builtin_amdgcn_alignbit(wa2, wa1, 16);              \
    xa2 = __builtin_amdgcn_alignbit(wa3, wa2, 16);              \
    xa3 = __builtin_amdgcn_alignbit(wa4, wa3, 16);              \
    xa4 = __builtin_amdgcn_alignbit(wa5, wa4, 16);              \
    xb0 = __builtin_amdgcn_alignbit(wb1, wb0, 16);              \
    xb1 = __builtin_amdgcn_alignbit(wb2, wb1, 16);              \
    xb2 = __builtin_amdgcn_alignbit(wb3, wb2, 16);              \
    xb3 = __builtin_amdgcn_alignbit(wb4, wb3, 16);              \
    xb4 = __builtin_amdgcn_alignbit(wb5, wb4, 16);

// one lower row: masks + both jobs
#define LOWROW(D)                                               \
    { LOADW(D)                                                  \
      ALIGNS5                                                   \
      float mv = 1.f;                                           \
      if constexpr (ER) mv = (v0 + ty + (D) < Hd) ? 1.f : 0.f;  \
      (void)mv;                                                 \
      ROWJOB(CA0,CB0, wa0,xa0,wa1,xa1,wa2,xa2,wa3,xa3,wa4,      \
                      wb0,xb0,wb1,xb1,wb2,xb2,wb3,xb3,wb4,      \
                      m_m4,m_m3,m_m2,m_m1,m_0,m_p1,m_p2,m_p3,m_p4, mv, p00,p01) \
      ROWJOB(CA1,CB1, wa1,xa1,wa2,xa2,wa3,xa3,wa4,xa4,wa5,      \
                      wb1,xb1,wb2,xb2,wb3,xb3,wb4,xb4,wb5,      \
                      m_m2,m_m1,m_0,m_p1,m_p2,m_p3,m_p4,m_p5,m_p6, mv, p10,p11) }

template<bool EC, bool ER>
__device__ __forceinline__ float strip_sum(const unsigned* __restrict__ sAb,
                                           const unsigned* __restrict__ sBb,
                                           int ty, int tx, int ub, int v0)
{
    const h2 h05 = { (__fp16)0.5f, (__fp16)0.5f };
    unsigned m_m4=0,m_m3=0,m_m2=0,m_m1=0,m_0=0,m_p1=0,m_p2=0,m_p3=0,m_p4=0,m_p5=0,m_p6=0;
    if constexpr (EC) {
        auto mk = [&](int k)->unsigned {
            unsigned lo = ((unsigned)(ub + k)     < (unsigned)Wd) ? 0x3C00u : 0u;
            unsigned hi = ((unsigned)(ub + k + 1) < (unsigned)Wd) ? 0x3C00u : 0u;
            return lo | (hi << 16);
        };
        m_m4=mk(-4); m_m3=mk(-3); m_m2=mk(-2); m_m1=mk(-1); m_0=mk(0);
        m_p1=mk(1);  m_p2=mk(2);  m_p3=mk(3);  m_p4=mk(4);  m_p5=mk(5); m_p6=mk(6);
    }

    const unsigned* pa = sAb + ty * SWP + 2 * tx;   // window base, this thread
    const unsigned* pb = sBb + ty * SWP + 2 * tx;

    unsigned wa0,wa1,wa2,wa3,wa4,wa5, wb0,wb1,wb2,wb3,wb4,wb5;
    unsigned xa0,xa1,xa2,xa3,xa4, xb0,xb1,xb2,xb3,xb4;
    float p00=0.f, p01=0.f, p10=0.f, p11=0.f;

    // ---- center row ----
    LOADW(0)
    ALIGNS5
    h2 CA0 = u2h(wa2), CB0 = u2h(wb2);   // job 0 centers (px ub, ub+1)
    h2 CA1 = u2h(wa3), CB1 = u2h(wb3);   // job 1 centers (px ub+2, ub+3)
    CTR4(CA0,CB0, xa2,wa3,xa3,wa4, xb2,wb3,xb3,wb4, m_p1,m_p2,m_p3,m_p4, p00,p01)
    CTR4(CA1,CB1, xa3,wa4,xa4,wa5, xb3,wb4,xb4,wb5, m_p3,m_p4,m_p5,m_p6, p10,p11)

    // ---- 4 lower rows, fully unrolled (literal LDS offsets) ----
    LOWROW(1)
    LOWROW(2)
    LOWROW(3)
    LOWROW(4)

    return (p00 + p01) + (p10 + p11);
}

// ---------------- Kernel B: packed-pair census over 64x16 tiles ----------------
__global__ __launch_bounds__(256)
void census_pk(const float* __restrict__ proj, const float* __restrict__ im,
               float* __restrict__ partial)
{
    __shared__ unsigned sA[(TH + RR) * SWP];   // proj pairs
    __shared__ unsigned sB[(TH + RR) * SWP];   // im pairs

    const int tU = blockIdx.x, tV = blockIdx.y, b = blockIdx.z;
    const int tid = threadIdx.x;
    const float* pb = proj + (size_t)b * HWsz;
    const float* ib = im   + (size_t)b * HWsz;
    const int v0  = tV * TH;
    const int u0g = tU * TW - 4;               // LDS col0 global col (even)

    const bool edgeC = (tU == 0) | (tU == TILES_X - 1);
    const bool edgeR = (tV == TILES_Y - 1);

    if (!edgeC && !edgeR) {
        const float* pbase = pb + v0 * Wd + u0g;
        const float* ibase = ib + v0 * Wd + u0g;
        for (int f = tid; f < (TH + RR) * 18; f += 256) {
            int r = f / 18;
            int c4 = (f - 18 * r) * 4;
            float4 va = *(const float4*)(pbase + r * Wd + c4);
            float4 vb = *(const float4*)(ibase + r * Wd + c4);
            uint2 qa = { pack2(va.x, va.y), pack2(va.z, va.w) };
            uint2 qb = { pack2(vb.x, vb.y), pack2(vb.z, vb.w) };
            *(uint2*)&sA[r * SWP + c4 / 2] = qa;
            *(uint2*)&sB[r * SWP + c4 / 2] = qb;
        }
    } else {
        for (int p = tid; p < (TH + RR) * 36; p += 256) {
            int r = p / 36;
            int q = p - 36 * r;
            int gv = min(v0 + r, Hd - 1);
            int g0 = min(max(u0g + 2 * q,     0), Wd - 1);
            int g1 = min(max(u0g + 2 * q + 1, 0), Wd - 1);
            const float* pr  = pb + (size_t)gv * Wd;
            const float* irow = ib + (size_t)gv * Wd;
            sA[r * SWP + q] = pack2(pr[g0],   pr[g1]);
            sB[r * SWP + q] = pack2(irow[g0], irow[g1]);
        }
    }
    __syncthreads();

    const int ty = tid >> 4;                    // 0..15 (row in tile)
    const int tx = tid & 15;                    // 0..15 (group of 4 px = 2 pairs)
    const int ub = tU * TW + 4 * tx;            // global col of px 0

    float acc;
    if (!edgeC && !edgeR)      acc = strip_sum<false,false>(sA, sB, ty, tx, ub, v0);
    else if (edgeC && !edgeR)  acc = strip_sum<true, false>(sA, sB, ty, tx, ub, v0);
    else if (!edgeC)           acc = strip_sum<false,true >(sA, sB, ty, tx, ub, v0);
    else                       acc = strip_sum<true, true >(sA, sB, ty, tx, ub, v0);

    // block reduction -> one partial per block (deterministic)
    #pragma unroll
    for (int o = 32; o; o >>= 1) acc += __shfl_down(acc, o);
    __shared__ float wsum[4];
    int wid = tid >> 6, lane = tid & 63;
    if (lane == 0) wsum[wid] = acc;
    __syncthreads();
    if (tid == 0) {
        float s = wsum[0] + wsum[1] + wsum[2] + wsum[3];
        partial[((int)blockIdx.z * gridDim.y + blockIdx.y) * gridDim.x + blockIdx.x] = s;
    }
}

// ---------------- Kernel C: final deterministic reduce ----------------
__global__ __launch_bounds__(1024)
void final_reduce(const float* __restrict__ partial, float* __restrict__ out)
{
    double s = 0.0;
    for (int i = threadIdx.x; i < NBLK; i += 1024) s += (double)partial[i];
    __shared__ double sm[1024];
    sm[threadIdx.x] = s;
    __syncthreads();
    for (int st = 512; st; st >>= 1) {
        if (threadIdx.x < st) sm[threadIdx.x] += sm[threadIdx.x + st];
        __syncthreads();
    }
    if (threadIdx.x == 0) {
        // val = 2 * S_half / (81 * B*H*W)   (half-space symmetry doubling)
        out[0] = (float)(sm[0] * (2.0 / (81.0 * (double)NB * Hd * Wd)));
    }
}

extern "C" void kernel_launch(void* const* d_in, const int* in_sizes, int n_in,
                              void* d_out, int out_size, void* d_ws, size_t ws_size,
                              hipStream_t stream)
{
    const float* disp    = (const float*)d_in[0];
    const float* im      = (const float*)d_in[1];
    const float* pattern = (const float*)d_in[2];
    float* out  = (float*)d_out;
    float* proj = out + 1;                      // output 1: pattern_proj
    float* partial = (float*)d_ws;              // 10240 floats scratch

    const int npx = NB * (int)HWsz;
    warp_kernel<<<npx / (256 * 4), 256, 0, stream>>>(disp, pattern, proj);

    dim3 grid(TILES_X, TILES_Y, NB);
    census_pk<<<grid, 256, 0, stream>>>(proj, im, partial);

    final_reduce<<<1, 1024, 0, stream>>>(partial, out);
}

// Round 15
// 117.628 us; speedup vs baseline: 2.2526x; 1.0015x over previous
//
#include <hip/hip_runtime.h>

#define Wd 640
#define Hd 512
#define NB 32
#define TW 64
#define TH2 32
#define RR 4
#define SWP 38                      // LDS row stride in u32 pairs (36 used + 2 pad)
#define ROWS2 (TH2 + RR)            // 36 staged rows
constexpr int TILES_X = Wd / TW;   // 10
constexpr int TILES_Y = Hd / TH2;  // 16
constexpr int NBLK = TILES_X * TILES_Y * NB;   // 5120
constexpr size_t HWsz = (size_t)Hd * Wd;

typedef __fp16 h2 __attribute__((ext_vector_type(2)));
union HU { unsigned u; h2 h; };
__device__ __forceinline__ h2 u2h(unsigned u){ HU c; c.u = u; return c.h; }
__device__ __forceinline__ h2 habs2(h2 x){ HU c; c.h = x; c.u &= 0x7fff7fffu; return c.h; }
__device__ __forceinline__ unsigned pack2(float a, float b)
{
    HU c; c.h = __builtin_amdgcn_cvt_pkrtz(a, b); return c.u;
}

// ---------------- Kernel A: disparity warp ----------------
__global__ __launch_bounds__(256)
void warp_kernel(const float* __restrict__ disp, const float* __restrict__ pattern,
                 float* __restrict__ proj)
{
    int gid = blockIdx.x * 256 + threadIdx.x;
    int n = gid * 4;
    float4 d4 = *(const float4*)(disp + n);
    int u = n % Wd;
    int rowbase = ((n / Wd) % Hd) * Wd;
    float dv[4] = {d4.x, d4.y, d4.z, d4.w};
    #pragma unroll
    for (int j = 0; j < 4; ++j) {
        float x = (float)(u + j) - dv[j];
        x = fminf(fmaxf(x, 0.f), (float)(Wd - 1));
        float x0 = floorf(x);
        float w = x - x0;
        int i0 = (int)x0;
        int i1 = min(i0 + 1, Wd - 1);
        float g0 = pattern[rowbase + i0];
        float g1 = pattern[rowbase + i1];
        proj[n + j] = fmaf(w, g1 - g0, g0);
    }
}

// ---------------- packed census primitives (r13/r14-proven) ----------------
#define PKTM(CA,CB, NAu,NBu, MM, N,E) {            \
    h2 _da = u2h(NAu) - CA;                        \
    h2 _db = u2h(NBu) - CB;                        \
    h2 _d1 = h05 + habs2(_da);                     \
    h2 _d2 = h05 + habs2(_db);                     \
    N = _da * _d2 - _db * _d1;                     \
    if constexpr (EC) N = N * u2h(MM);             \
    E = _d1 * _d2; }

#define L1C(N1,E1,N2,E2, SP,EP) {                  \
    SP = habs2(N1) * E2 + habs2(N2) * E1;          \
    EP = E1 * E2; }

#define UNP(S,E, MV, P0,P1) {                      \
    float _sl = (float)S[0], _sh = (float)S[1];    \
    float _el = (float)E[0], _eh = (float)E[1];    \
    if constexpr (ER) { _sl *= MV; _sh *= MV; }    \
    P0 = fmaf(_sl, __builtin_amdgcn_rcpf(_el), P0);\
    P1 = fmaf(_sh, __builtin_amdgcn_rcpf(_eh), P1); }

#define ROWJOB(CA,CB, A0,A1,A2,A3,A4,A5,A6,A7,A8,  \
                      B0,B1,B2,B3,B4,B5,B6,B7,B8,  \
                      M0,M1,M2,M3,M4,M5,M6,M7,M8, MV, P0,P1) { \
    h2 n0,e0,n1,e1,n2,e2,n3,e3,n4,e4,n5,e5,n6,e6,n7,e7,n8,e8; \
    PKTM(CA,CB, A0,B0, M0, n0,e0)                  \
    PKTM(CA,CB, A1,B1, M1, n1,e1)                  \
    PKTM(CA,CB, A2,B2, M2, n2,e2)                  \
    PKTM(CA,CB, A3,B3, M3, n3,e3)                  \
    PKTM(CA,CB, A4,B4, M4, n4,e4)                  \
    PKTM(CA,CB, A5,B5, M5, n5,e5)                  \
    PKTM(CA,CB, A6,B6, M6, n6,e6)                  \
    PKTM(CA,CB, A7,B7, M7, n7,e7)                  \
    PKTM(CA,CB, A8,B8, M8, n8,e8)                  \
    h2 s01,e01,s23,e23,s45,e45,s67,e67;            \
    L1C(n0,e0,n1,e1, s01,e01)                      \
    L1C(n2,e2,n3,e3, s23,e23)                      \
    L1C(n4,e4,n5,e5, s45,e45)                      \
    L1C(n6,e6,n7,e7, s67,e67)                      \
    h2 sL = s01*e23 + s23*e01;  h2 eL = e01*e23;   \
    h2 sR = s45*e67 + s67*e45;  h2 eR = e45*e67;   \
    sR = sR*e8 + habs2(n8)*eR;  eR = eR*e8;        \
    h2 S = sL*eR + sR*eL;       h2 E = eL*eR;      \
    UNP(S,E, MV, P0,P1) }

#define CTR4(CA,CB, A1,A2,A3,A4, B1,B2,B3,B4, M1,M2,M3,M4, P0,P1) { \
    h2 n1,e1,n2,e2,n3,e3,n4,e4;                    \
    PKTM(CA,CB, A1,B1, M1, n1,e1)                  \
    PKTM(CA,CB, A2,B2, M2, n2,e2)                  \
    PKTM(CA,CB, A3,B3, M3, n3,e3)                  \
    PKTM(CA,CB, A4,B4, M4, n4,e4)                  \
    h2 sA,eA,sB,eB,s4,e4t;                         \
    L1C(n1,e1,n2,e2, sA,eA)                        \
    L1C(n3,e3,n4,e4, sB,eB)                        \
    s4 = sA*eB + sB*eA; e4t = eA*eB;               \
    { float _sl = (float)s4[0], _sh = (float)s4[1];            \
      float _el = (float)e4t[0], _eh = (float)e4t[1];          \
      P0 = fmaf(_sl, __builtin_amdgcn_rcpf(_el), P0);          \
      P1 = fmaf(_sh, __builtin_amdgcn_rcpf(_eh), P1); } }

#define LOADW(D)                                                \
    { const uint2* _pa = (const uint2*)(pa + (D) * SWP);        \
      const uint2* _pb = (const uint2*)(pb + (D) * SWP);        \
      uint2 _a0 = _pa[0], _a1 = _pa[1], _a2 = _pa[2];           \
      uint2 _b0 = _pb[0], _b1 = _pb[1], _b2 = _pb[2];           \
      wa0=_a0.x; wa1=_a0.y; wa2=_a1.x; wa3=_a1.y; wa4=_a2.x; wa5=_a2.y; \
      wb0=_b0.x; wb1=_b0.y; wb2=_b1.x; wb3=_b1.y; wb4=_b2.x; wb5=_b2.y; }

#define ALIGNS5                                                 \
    xa0 = __builtin_amdgcn_alignbit(wa1, wa0, 16);              \
    xa1 = __builtin_amdgcn_alignbit(wa2, wa1, 16);              \
    xa2 = __builtin_amdgcn_alignbit(wa3, wa2, 16);              \
    xa3 = __builtin_amdgcn_alignbit(wa4, wa3, 16);              \
    xa4 = __builtin_amdgcn_alignbit(wa5, wa4, 16);              \
    xb0 = __builtin_amdgcn_alignbit(wb1, wb0, 16);              \
    xb1 = __builtin_amdgcn_alignbit(wb2, wb1, 16);              \
    xb2 = __builtin_amdgcn_alignbit(wb3, wb2, 16);              \
    xb3 = __builtin_amdgcn_alignbit(wb4, wb3, 16);              \
    xb4 = __builtin_amdgcn_alignbit(wb5, wb4, 16);

#define LOWROW(D)                                               \
    { LOADW(D)                                                  \
      ALIGNS5                                                   \
      float mv = 1.f;                                           \
      if constexpr (ER) mv = (gr + (D) < Hd) ? 1.f : 0.f;       \
      (void)mv;                                                 \
      ROWJOB(CA0,CB0, wa0,xa0,wa1,xa1,wa2,xa2,wa3,xa3,wa4,      \
                      wb0,xb0,wb1,xb1,wb2,xb2,wb3,xb3,wb4,      \
                      m_m4,m_m3,m_m2,m_m1,m_0,m_p1,m_p2,m_p3,m_p4, mv, p00,p01) \
      ROWJOB(CA1,CB1, wa1,xa1,wa2,xa2,wa3,xa3,wa4,xa4,wa5,      \
                      wb1,xb1,wb2,xb2,wb3,xb3,wb4,xb4,wb5,      \
                      m_m2,m_m1,m_0,m_p1,m_p2,m_p3,m_p4,m_p5,m_p6, mv, p10,p11) }

// one 4-px strip: pa/pb point at the strip's center-row window; gr = global center row
template<bool EC, bool ER>
__device__ __forceinline__ float strip_sum(const unsigned* __restrict__ pa,
                                           const unsigned* __restrict__ pb,
                                           int ub, int gr)
{
    const h2 h05 = { (__fp16)0.5f, (__fp16)0.5f };
    unsigned m_m4=0,m_m3=0,m_m2=0,m_m1=0,m_0=0,m_p1=0,m_p2=0,m_p3=0,m_p4=0,m_p5=0,m_p6=0;
    if constexpr (EC) {
        auto mk = [&](int k)->unsigned {
            unsigned lo = ((unsigned)(ub + k)     < (unsigned)Wd) ? 0x3C00u : 0u;
            unsigned hi = ((unsigned)(ub + k + 1) < (unsigned)Wd) ? 0x3C00u : 0u;
            return lo | (hi << 16);
        };
        m_m4=mk(-4); m_m3=mk(-3); m_m2=mk(-2); m_m1=mk(-1); m_0=mk(0);
        m_p1=mk(1);  m_p2=mk(2);  m_p3=mk(3);  m_p4=mk(4);  m_p5=mk(5); m_p6=mk(6);
    }

    unsigned wa0,wa1,wa2,wa3,wa4,wa5, wb0,wb1,wb2,wb3,wb4,wb5;
    unsigned xa0,xa1,xa2,xa3,xa4, xb0,xb1,xb2,xb3,xb4;
    float p00=0.f, p01=0.f, p10=0.f, p11=0.f;

    LOADW(0)
    ALIGNS5
    h2 CA0 = u2h(wa2), CB0 = u2h(wb2);   // job 0 centers (px ub, ub+1)
    h2 CA1 = u2h(wa3), CB1 = u2h(wb3);   // job 1 centers (px ub+2, ub+3)
    CTR4(CA0,CB0, xa2,wa3,xa3,wa4, xb2,wb3,xb3,wb4, m_p1,m_p2,m_p3,m_p4, p00,p01)
    CTR4(CA1,CB1, xa3,wa4,xa4,wa5, xb3,wb4,xb4,wb5, m_p3,m_p4,m_p5,m_p6, p10,p11)

    LOWROW(1)
    LOWROW(2)
    LOWROW(3)
    LOWROW(4)

    return (p00 + p01) + (p10 + p11);
}

// ---------------- Kernel B: packed-pair census over 64x32 tiles ----------------
// thread = 4-px column group; strip 1 at row ty, strip 2 at row ty+16 (sequential)
__global__ __launch_bounds__(256)
void census_pk(const float* __restrict__ proj, const float* __restrict__ im,
               float* __restrict__ partial)
{
    __shared__ unsigned sA[ROWS2 * SWP];   // proj pairs, 36 x 38 u32
    __shared__ unsigned sB[ROWS2 * SWP];   // im pairs

    const int tU = blockIdx.x, tV = blockIdx.y, b = blockIdx.z;
    const int tid = threadIdx.x;
    const float* pb = proj + (size_t)b * HWsz;
    const float* ib = im   + (size_t)b * HWsz;
    const int v0  = tV * TH2;
    const int u0g = tU * TW - 4;               // LDS col0 global col (even)

    const bool edgeC = (tU == 0) | (tU == TILES_X - 1);
    const bool edgeR = (tV == TILES_Y - 1);

    if (!edgeC && !edgeR) {
        const float* pbase = pb + v0 * Wd + u0g;
        const float* ibase = ib + v0 * Wd + u0g;
        for (int f = tid; f < ROWS2 * 18; f += 256) {
            int r = f / 18;
            int c4 = (f - 18 * r) * 4;
            float4 va = *(const float4*)(pbase + r * Wd + c4);
            float4 vb = *(const float4*)(ibase + r * Wd + c4);
            uint2 qa = { pack2(va.x, va.y), pack2(va.z, va.w) };
            uint2 qb = { pack2(vb.x, vb.y), pack2(vb.z, vb.w) };
            *(uint2*)&sA[r * SWP + c4 / 2] = qa;
            *(uint2*)&sB[r * SWP + c4 / 2] = qb;
        }
    } else {
        for (int p = tid; p < ROWS2 * 36; p += 256) {
            int r = p / 36;
            int q = p - 36 * r;
            int gv = min(v0 + r, Hd - 1);
            int g0 = min(max(u0g + 2 * q,     0), Wd - 1);
            int g1 = min(max(u0g + 2 * q + 1, 0), Wd - 1);
            const float* pr   = pb + (size_t)gv * Wd;
            const float* irow = ib + (size_t)gv * Wd;
            sA[r * SWP + q] = pack2(pr[g0],   pr[g1]);
            sB[r * SWP + q] = pack2(irow[g0], irow[g1]);
        }
    }
    __syncthreads();

    const int ty = tid >> 4;                    // 0..15
    const int tx = tid & 15;                    // 0..15 (4 px = 2 pairs)
    const int ub = tU * TW + 4 * tx;            // global col of px 0

    const unsigned* pa1 = sA + ty * SWP + 2 * tx;
    const unsigned* pb1 = sB + ty * SWP + 2 * tx;
    const unsigned* pa2 = pa1 + 16 * SWP;
    const unsigned* pb2 = pb1 + 16 * SWP;
    const int gr1 = v0 + ty, gr2 = gr1 + 16;

    // strip 1 windows reach row v0+ty+4 <= v0+19 <= 511 even for the last tile row
    // -> ER only ever needed on strip 2.
    float acc;
    if (!edgeC) {
        acc  = strip_sum<false,false>(pa1, pb1, ub, gr1);
        acc += edgeR ? strip_sum<false,true >(pa2, pb2, ub, gr2)
                     : strip_sum<false,false>(pa2, pb2, ub, gr2);
    } else {
        acc  = strip_sum<true, false>(pa1, pb1, ub, gr1);
        acc += edgeR ? strip_sum<true, true >(pa2, pb2, ub, gr2)
                     : strip_sum<true, false>(pa2, pb2, ub, gr2);
    }

    // block reduction -> one partial per block (deterministic)
    #pragma unroll
    for (int o = 32; o; o >>= 1) acc += __shfl_down(acc, o);
    __shared__ float wsum[4];
    int wid = tid >> 6, lane = tid & 63;
    if (lane == 0) wsum[wid] = acc;
    __syncthreads();
    if (tid == 0) {
        float s = wsum[0] + wsum[1] + wsum[2] + wsum[3];
        partial[((int)blockIdx.z * gridDim.y + blockIdx.y) * gridDim.x + blockIdx.x] = s;
    }
}

// ---------------- Kernel C: final deterministic reduce ----------------
__global__ __launch_bounds__(1024)
void final_reduce(const float* __restrict__ partial, float* __restrict__ out)
{
    double s = 0.0;
    for (int i = threadIdx.x; i < NBLK; i += 1024) s += (double)partial[i];
    __shared__ double sm[1024];
    sm[threadIdx.x] = s;
    __syncthreads();
    for (int st = 512; st; st >>= 1) {
        if (threadIdx.x < st) sm[threadIdx.x] += sm[threadIdx.x + st];
        __syncthreads();
    }
    if (threadIdx.x == 0) {
        // val = 2 * S_half / (81 * B*H*W)   (half-space symmetry doubling)
        out[0] = (float)(sm[0] * (2.0 / (81.0 * (double)NB * Hd * Wd)));
    }
}

extern "C" void kernel_launch(void* const* d_in, const int* in_sizes, int n_in,
                              void* d_out, int out_size, void* d_ws, size_t ws_size,
                              hipStream_t stream)
{
    const float* disp    = (const float*)d_in[0];
    const float* im      = (const float*)d_in[1];
    const float* pattern = (const float*)d_in[2];
    float* out  = (float*)d_out;
    float* proj = out + 1;                      // output 1: pattern_proj
    float* partial = (float*)d_ws;              // 5120 floats scratch

    const int npx = NB * (int)HWsz;
    warp_kernel<<<npx / (256 * 4), 256, 0, stream>>>(disp, pattern, proj);

    dim3 grid(TILES_X, TILES_Y, NB);
    census_pk<<<grid, 256, 0, stream>>>(proj, im, partial);

    final_reduce<<<1, 1024, 0, stream>>>(partial, out);
}